// Round 14
// baseline (120.108 us; speedup 1.0000x reference)
//
#include <hip/hip_runtime.h>
#include <cstdint>
#include <cstddef>

#define N_SEQ 4096
#define D_HEAD 128
#define KP_DIM 256

typedef __attribute__((ext_vector_type(4))) float f32x4;
typedef __attribute__((ext_vector_type(8))) short bf16x8;
typedef __attribute__((ext_vector_type(2))) unsigned int u32x2;

static __device__ __forceinline__ short f2bf(float f) {
  uint32_t u = __builtin_bit_cast(uint32_t, f);
  u += 0x7FFFu + ((u >> 16) & 1u);
  return (short)(u >> 16);
}

static __device__ __forceinline__ unsigned int cvtpk(float a, float b) {
  unsigned int r;
  asm("v_cvt_pk_bf16_f32 %0, %1, %2" : "=v"(r) : "v"(a), "v"(b));
  return r;
}

static __device__ __forceinline__ int swz8(int r) { return (r ^ (r >> 2)) & 7; }

// ---------------------------------------------------------------------------
// Stage 0: convert E_W,F_W f32 -> bf16 wbf[2][256][4096] (d_out scratch)
// ---------------------------------------------------------------------------
__global__ __launch_bounds__(256) void conv_w_kernel(
    const float* __restrict__ EW, const float* __restrict__ FW,
    short* __restrict__ wbf) {
  const int idx = blockIdx.x * 256 + threadIdx.x;
  const int half = 262144;
  f32x4 v = (idx < half) ? *(const f32x4*)(EW + (size_t)idx * 4)
                         : *(const f32x4*)(FW + (size_t)(idx - half) * 4);
  u32x2 h = {cvtpk(v[0], v[1]), cvtpk(v[2], v[3])};
  *(u32x2*)(wbf + (size_t)idx * 4) = h;
}

// ---------------------------------------------------------------------------
// Stage 1 (v8): partial projections. grid 256 (1 block/CU, XCD-chunked),
// 1024 thr = 16 waves = 8 tile-slots (4k x 2d of 64x64) x 2 n-halves.
// W A-frags DIRECT from L2 (16B/lane contiguous, issued at iter start,
// covered by counted vmcnt) -> NO W LDS. LDS = X^T tile 16KB x2 + 32KB merge.
// Per iter: 1 vmcnt + 1 barrier. n-halves merged through LDS at the end (f32).
// pws[b][p][s][k 256][d 128] f32 partials.
// ---------------------------------------------------------------------------
__global__ __launch_bounds__(1024, 4) void proj_partial_kernel(
    const float* __restrict__ Kin, const float* __restrict__ Vin,
    const short* __restrict__ wbf, float* __restrict__ pws) {
  const int bid = blockIdx.x;                  // 0..255
  const int wk = (bid & 7) * 32 + (bid >> 3);  // XCD x owns wk [32x, 32x+32)
  const int b = wk & 31;
  const int s = (wk >> 5) & 3;
  const int p = wk >> 7;

  const float* __restrict__ X = (p == 0 ? Kin : Vin) + (size_t)b * (N_SEQ * D_HEAD);
  const short* __restrict__ wp = wbf + (size_t)p * (KP_DIM * N_SEQ);
  float* __restrict__ outp = pws + ((((size_t)b * 2 + p) * 4) + s) * (KP_DIM * D_HEAD);

  __shared__ __align__(16) short xt[2][D_HEAD * 64];  // 16KB x2: X^T [128 d][64 n]
  __shared__ __align__(16) float mrg[2][64 * 64];     // 32KB: n-half merge (2 slots/phase)

  const int t = threadIdx.x;
  const int lane = t & 63;
  const int w = t >> 6;            // 0..15
  const int slot = w & 7;          // 8 tile slots
  const int half = w >> 3;         // n-half 0/1
  const int wkk = (slot >> 1) * 64;  // k offset (4 groups of 64)
  const int wdd = (slot & 1) * 64;   // d offset (2 groups of 64)
  const int nh = half * 32;          // n-half offset within BK=64
  const int l15 = lane & 15;
  const int l4 = lane >> 4;
  const int dq = t & 31;           // d-quad for X staging
  const int ng = t >> 5;           // n-pair group (0..31) for X staging

  const int n0 = s * 1024;

  f32x4 acc[4][4];
#pragma unroll
  for (int i = 0; i < 4; ++i)
#pragma unroll
    for (int j = 0; j < 4; ++j) acc[i][j] = (f32x4){0.f, 0.f, 0.f, 0.f};

  f32x4 xA[2], xB[2];  // depth-2 X prefetch

#define PROJ_XISSUE(XR, NC)                                                         \
  do {                                                                              \
    _Pragma("unroll") for (int i_ = 0; i_ < 2; ++i_)                                \
      XR[i_] = *(const f32x4*)(X + (size_t)((NC) + ng * 2 + i_) * D_HEAD + dq * 4); \
  } while (0)

#define PROJ_XCVT(XR, BUF)                                                          \
  do {                                                                              \
    _Pragma("unroll") for (int j_ = 0; j_ < 4; ++j_) {                              \
      int drow_ = dq * 4 + j_;                                                      \
      unsigned int hv_ = cvtpk(XR[0][j_], XR[1][j_]);                               \
      *(unsigned int*)(&xt[BUF][drow_ * 64 + ((ng * 2) ^ (swz8(drow_) << 3))]) = hv_; \
    }                                                                               \
  } while (0)

#define PROJ_WLOAD(WA, NN)                                                          \
  do {                                                                              \
    _Pragma("unroll") for (int mt_ = 0; mt_ < 4; ++mt_)                             \
      WA[mt_] = *(const bf16x8*)(wp + (size_t)(wkk + mt_ * 16 + l15) * N_SEQ +      \
                                 (NN) + nh + l4 * 8);                               \
  } while (0)

#define PROJ_COMPUTE(CUR, WA)                                                       \
  do {                                                                              \
    bf16x8 bb_[4];                                                                  \
    _Pragma("unroll") for (int nt_ = 0; nt_ < 4; ++nt_) {                           \
      int row_ = wdd + nt_ * 16 + l15;                                              \
      bb_[nt_] = *(const bf16x8*)(&xt[CUR][row_ * 64 +                              \
                                           ((nh + l4 * 8) ^ (swz8(row_) << 3))]);   \
    }                                                                               \
    _Pragma("unroll") for (int mt_ = 0; mt_ < 4; ++mt_)                             \
      _Pragma("unroll") for (int nt_ = 0; nt_ < 4; ++nt_)                           \
        acc[mt_][nt_] = __builtin_amdgcn_mfma_f32_16x16x32_bf16(WA[mt_], bb_[nt_],  \
                                                                acc[mt_][nt_], 0, 0, 0); \
  } while (0)

  // ---- prologue: X(0) staged, X(1) in flight ----
  PROJ_XISSUE(xA, n0);
  asm volatile("s_waitcnt vmcnt(0)" ::: "memory");
  PROJ_XCVT(xA, 0);
  PROJ_XISSUE(xB, n0 + 64);  // X(1): 2 outstanding
  __syncthreads();

  // ---- main loop: iters 0..13 as 7 even/odd pairs ----
  for (int itp = 0; itp < 7; ++itp) {
    const int it0 = itp * 2;
    {  // even iter (cur=0)
      const int nn = n0 + it0 * 64;
      bf16x8 wa[4];
      PROJ_WLOAD(wa, nn);                              // W(it): +4
      PROJ_XISSUE(xA, nn + 128);                       // X(it+2): +2
      asm volatile("s_waitcnt vmcnt(2)" ::: "memory"); // W(it)+X(it+1) done
      PROJ_XCVT(xB, 1);                                // X(it+1) -> xt[1]
      PROJ_COMPUTE(0, wa);
      __syncthreads();
    }
    {  // odd iter (cur=1)
      const int nn = n0 + (it0 + 1) * 64;
      bf16x8 wa[4];
      PROJ_WLOAD(wa, nn);
      PROJ_XISSUE(xB, nn + 128);
      asm volatile("s_waitcnt vmcnt(2)" ::: "memory");
      PROJ_XCVT(xA, 0);
      PROJ_COMPUTE(1, wa);
      __syncthreads();
    }
  }
  {  // it=14 (cur=0): no more X issues
    const int nn = n0 + 14 * 64;
    bf16x8 wa[4];
    PROJ_WLOAD(wa, nn);                                // +4 (X(15): 2 outstanding)
    asm volatile("s_waitcnt vmcnt(0)" ::: "memory");   // all done
    PROJ_XCVT(xB, 1);                                  // X(15) -> xt[1]
    PROJ_COMPUTE(0, wa);
    __syncthreads();
  }
  {  // it=15 (cur=1)
    const int nn = n0 + 15 * 64;
    bf16x8 wa[4];
    PROJ_WLOAD(wa, nn);
    asm volatile("s_waitcnt vmcnt(0)" ::: "memory");
    PROJ_COMPUTE(1, wa);
  }

#undef PROJ_XISSUE
#undef PROJ_XCVT
#undef PROJ_WLOAD
#undef PROJ_COMPUTE

  // ---- merge n-halves: 4 phases, 2 slots per phase through 32KB LDS ----
  __syncthreads();
#pragma unroll
  for (int ph = 0; ph < 4; ++ph) {
    if (half == 1 && (slot >> 1) == ph) {
      float* m = &mrg[slot & 1][0];
#pragma unroll
      for (int mt = 0; mt < 4; ++mt)
#pragma unroll
        for (int nt = 0; nt < 4; ++nt)
#pragma unroll
          for (int r = 0; r < 4; ++r)
            m[(mt * 16 + l4 * 4 + r) * 64 + nt * 16 + l15] = acc[mt][nt][r];
    }
    __syncthreads();
    if (half == 0 && (slot >> 1) == ph) {
      const float* m = &mrg[slot & 1][0];
#pragma unroll
      for (int mt = 0; mt < 4; ++mt)
#pragma unroll
        for (int nt = 0; nt < 4; ++nt)
#pragma unroll
          for (int r = 0; r < 4; ++r)
            acc[mt][nt][r] += m[(mt * 16 + l4 * 4 + r) * 64 + nt * 16 + l15];
    }
    __syncthreads();
  }

  // ---- write f32 partials (half-0 waves only) ----
  if (half == 0) {
#pragma unroll
    for (int mt = 0; mt < 4; ++mt)
#pragma unroll
      for (int nt = 0; nt < 4; ++nt)
#pragma unroll
        for (int r = 0; r < 4; ++r) {
          int kk = wkk + mt * 16 + l4 * 4 + r;
          int dd = wdd + nt * 16 + l15;
          outp[kk * D_HEAD + dd] = acc[mt][nt][r];
        }
  }
}

// ---------------------------------------------------------------------------
// Stage 1b: reduce 4 partials + bias. grid 128 (unchanged).
// ---------------------------------------------------------------------------
__global__ __launch_bounds__(256) void reduce_bias_kernel(
    const float* __restrict__ pws, const float* __restrict__ Eb,
    const float* __restrict__ Fb, short* __restrict__ kp, short* __restrict__ vpt) {
  const int sub = blockIdx.x & 3;
  const int b = blockIdx.x >> 2;
  const int t = threadIdx.x;
  __shared__ short tile[128 * 128];
  if (sub < 2) {
    const float* __restrict__ base = pws + ((size_t)b * 2) * 4 * 32768;
    const int off = sub * 16384;
    for (int i = t; i < 16384; i += 256) {
      int ii = off + i;
      int k = ii >> 7;
      float v = base[ii] + base[ii + 32768] + base[ii + 65536] + base[ii + 98304] + Eb[k];
      kp[(size_t)b * 32768 + ii] = f2bf(v);
    }
  } else {
    const int kh = sub - 2;
    const float* __restrict__ base = pws + (((size_t)b * 2 + 1) * 4) * 32768 + kh * 16384;
    for (int i = t; i < 16384; i += 256) {
      int kl = i >> 7, d = i & 127;
      float v = base[i] + base[i + 32768] + base[i + 65536] + base[i + 98304] + Fb[kh * 128 + kl];
      tile[kl * 128 + (d ^ ((kl & 15) << 3))] = f2bf(v);
    }
    __syncthreads();
    for (int i = t; i < 16384; i += 256) {
      int d = i >> 7, kl = i & 127;
      vpt[(size_t)b * 32768 + d * 256 + kh * 128 + kl] = tile[kl * 128 + (d ^ ((kl & 15) << 3))];
    }
  }
}

// ---------------------------------------------------------------------------
// Stage 2: attention v4 (unchanged, verified). grid 256, 1024 thr,
// __launch_bounds__(1024,4), 160KB LDS, zero mid-loop barriers.
// ---------------------------------------------------------------------------
__global__ __launch_bounds__(1024, 4) void attn_kernel(
    const float* __restrict__ Q, const short* __restrict__ kp,
    const short* __restrict__ vpt, float* __restrict__ out) {
  const int bid = blockIdx.x;
  const int wk = (bid & 7) * 32 + (bid >> 3);  // XCD-chunked: 4 b's per XCD
  const int b = wk >> 3;
  const int slice = wk & 7;
  const int t = threadIdx.x;
  const int lane = t & 63;
  const int w = t >> 6;  // 0..15
  const int l15 = lane & 15, l4 = lane >> 4;

  __shared__ __align__(16) short lbuf[81920];
  short* lkp = lbuf;
  short* lvpt = lbuf + 32768;
  short* lpw = lbuf + 65536 + w * 1024;  // 2KB/wave

  const short* __restrict__ kpb = kp + (size_t)b * 32768;
  const short* __restrict__ vptb = vpt + (size_t)b * 32768;

#pragma unroll
  for (int i = 0; i < 4; ++i) {
    int g = t + i * 1024;
    int row = g >> 4, c = g & 15;
    __builtin_amdgcn_global_load_lds(
        (const __attribute__((address_space(1))) void*)(kpb + (size_t)row * 128 +
                                                        ((c ^ (row & 7)) << 3)),
        (__attribute__((address_space(3))) void*)(&lkp[g * 8]), 16, 0, 0);
  }
#pragma unroll
  for (int i = 0; i < 4; ++i) {
    int g = t + i * 1024;
    int row = g >> 5, c = g & 31;
    __builtin_amdgcn_global_load_lds(
        (const __attribute__((address_space(1))) void*)(vptb + (size_t)row * 256 +
                                                        ((c ^ (row & 7)) << 3)),
        (__attribute__((address_space(3))) void*)(&lvpt[g * 8]), 16, 0, 0);
  }

  const float scale = 0.08838834764831845f;  // 1/sqrt(128)
  f32x4 qraw[8];
  {
    const float* qr = Q + ((size_t)b * N_SEQ + slice * 512 + w * 16 + l15) * D_HEAD;
#pragma unroll
    for (int ks = 0; ks < 4; ++ks) {
      qraw[2 * ks] = *(const f32x4*)(qr + ks * 32 + l4 * 8);
      qraw[2 * ks + 1] = *(const f32x4*)(qr + ks * 32 + l4 * 8 + 4);
    }
  }
  asm volatile("s_waitcnt vmcnt(0)" ::: "memory");
  __syncthreads();

#pragma unroll
  for (int rd = 0; rd < 2; ++rd) {
    const int rowBase = slice * 512 + rd * 256 + w * 16;

    bf16x8 qf[4];
#pragma unroll
    for (int ks = 0; ks < 4; ++ks) {
      union { unsigned int u[4]; bf16x8 v; } cv;
      cv.u[0] = cvtpk(qraw[2 * ks][0] * scale, qraw[2 * ks][1] * scale);
      cv.u[1] = cvtpk(qraw[2 * ks][2] * scale, qraw[2 * ks][3] * scale);
      cv.u[2] = cvtpk(qraw[2 * ks + 1][0] * scale, qraw[2 * ks + 1][1] * scale);
      cv.u[3] = cvtpk(qraw[2 * ks + 1][2] * scale, qraw[2 * ks + 1][3] * scale);
      qf[ks] = cv.v;
    }

    f32x4 accs[16];
#pragma unroll
    for (int i = 0; i < 16; ++i) accs[i] = (f32x4){0.f, 0.f, 0.f, 0.f};
#pragma unroll
    for (int ks = 0; ks < 4; ++ks) {
#pragma unroll
      for (int nt = 0; nt < 16; ++nt) {
        bf16x8 af = *(const bf16x8*)(&lkp[(nt * 16 + l15) * 128 +
                                          (((ks * 4 + l4) ^ (l15 & 7)) << 3)]);
        accs[nt] = __builtin_amdgcn_mfma_f32_16x16x32_bf16(af, qf[ks], accs[nt], 0, 0, 0);
      }
    }

    float m = -1e30f;
#pragma unroll
    for (int nt = 0; nt < 16; ++nt)
#pragma unroll
      for (int r = 0; r < 4; ++r) m = fmaxf(m, accs[nt][r]);
    m = fmaxf(m, __shfl_xor(m, 16));
    m = fmaxf(m, __shfl_xor(m, 32));
    float s = 0.f;
#pragma unroll
    for (int nt = 0; nt < 16; ++nt)
#pragma unroll
      for (int r = 0; r < 4; ++r) {
        float e = __expf(accs[nt][r] - m);
        accs[nt][r] = e;
        s += e;
      }
    s += __shfl_xor(s, 16);
    s += __shfl_xor(s, 32);
    float inv = 1.0f / s;

    f32x4 acco[8];
#pragma unroll
    for (int i = 0; i < 8; ++i) acco[i] = (f32x4){0.f, 0.f, 0.f, 0.f};
#pragma unroll
    for (int qq = 0; qq < 4; ++qq) {
#pragma unroll
      for (int ntl = 0; ntl < 4; ++ntl) {
        int nt = qq * 4 + ntl;
        int cw = 2 * ntl + (l4 >> 1);
        unsigned int p0 = cvtpk(accs[nt][0] * inv, accs[nt][1] * inv);
        unsigned int p1 = cvtpk(accs[nt][2] * inv, accs[nt][3] * inv);
        *(u32x2*)((char*)lpw + l15 * 128 + ((cw ^ (l15 & 7)) << 4) + (l4 & 1) * 8) =
            (u32x2){p0, p1};
      }
      if (rd == 0 && qq == 3) {
        const float* qr = Q + ((size_t)b * N_SEQ + slice * 512 + 256 + w * 16 + l15) * D_HEAD;
#pragma unroll
        for (int ks = 0; ks < 4; ++ks) {
          qraw[2 * ks] = *(const f32x4*)(qr + ks * 32 + l4 * 8);
          qraw[2 * ks + 1] = *(const f32x4*)(qr + ks * 32 + l4 * 8 + 4);
        }
      }
#pragma unroll
      for (int ksl = 0; ksl < 2; ++ksl) {
        bf16x8 pa = *(const bf16x8*)((char*)lpw + l15 * 128 +
                                     (((4 * ksl + l4) ^ (l15 & 7)) << 4));
        int ksa = qq * 2 + ksl;
#pragma unroll
        for (int ntv = 0; ntv < 8; ++ntv) {
          bf16x8 av = *(const bf16x8*)(&lvpt[(ntv * 16 + l15) * 256 +
                                             (((ksa * 4 + l4) ^ (l15 & 7)) << 3)]);
          acco[ntv] = __builtin_amdgcn_mfma_f32_16x16x32_bf16(av, pa, acco[ntv], 0, 0, 0);
        }
      }
    }

    float* ob = out + ((size_t)b * N_SEQ + rowBase) * D_HEAD;
#pragma unroll
    for (int ntv = 0; ntv < 8; ++ntv)
      *(f32x4*)(ob + (size_t)l15 * D_HEAD + ntv * 16 + l4 * 4) = acco[ntv];
  }
}

// ---------------------------------------------------------------------------
extern "C" void kernel_launch(void* const* d_in, const int* in_sizes, int n_in,
                              void* d_out, int out_size, void* d_ws, size_t ws_size,
                              hipStream_t stream) {
  const float* Q  = (const float*)d_in[0];
  const float* K  = (const float*)d_in[1];
  const float* V  = (const float*)d_in[2];
  const float* EW = (const float*)d_in[3];
  const float* Eb = (const float*)d_in[4];
  const float* FW = (const float*)d_in[5];
  const float* Fb = (const float*)d_in[6];
  float* out = (float*)d_out;

  // d_out scratch (dead before attn writes): [0,4MB) wbf; [8MB,41.5MB) pws
  short* wbf = (short*)d_out;
  float* pws = (float*)d_out + 2097152;
  short* kpb = (short*)d_ws;
  short* vpt = (short*)((char*)d_ws + (size_t)32 * KP_DIM * D_HEAD * 2);

  conv_w_kernel<<<dim3(2048), dim3(256), 0, stream>>>(EW, FW, wbf);
  proj_partial_kernel<<<dim3(256), dim3(1024), 0, stream>>>(K, V, wbf, pws);
  reduce_bias_kernel<<<dim3(128), dim3(256), 0, stream>>>(pws, Eb, Fb, kpb, vpt);
  attn_kernel<<<dim3(256), dim3(1024), 0, stream>>>(Q, kpb, vpt, out);
}

// Round 15
// 95.868 us; speedup vs baseline: 1.2529x; 1.2529x over previous
//
#include <hip/hip_runtime.h>
#include <cstdint>
#include <cstddef>

#define N_SEQ 4096
#define D_HEAD 128
#define KP_DIM 256

typedef __attribute__((ext_vector_type(4))) float f32x4;
typedef __attribute__((ext_vector_type(8))) short bf16x8;
typedef __attribute__((ext_vector_type(2))) unsigned int u32x2;

static __device__ __forceinline__ short f2bf(float f) {
  uint32_t u = __builtin_bit_cast(uint32_t, f);
  u += 0x7FFFu + ((u >> 16) & 1u);
  return (short)(u >> 16);
}

static __device__ __forceinline__ unsigned int cvtpk(float a, float b) {
  unsigned int r;
  asm("v_cvt_pk_bf16_f32 %0, %1, %2" : "=v"(r) : "v"(a), "v"(b));
  return r;
}

static __device__ __forceinline__ int swz8(int r) { return (r ^ (r >> 2)) & 7; }

// ---------------------------------------------------------------------------
// Stage 0: convert E_W,F_W f32 -> bf16 wbf[2][256][4096] (d_out scratch)
// ---------------------------------------------------------------------------
__global__ __launch_bounds__(256) void conv_w_kernel(
    const float* __restrict__ EW, const float* __restrict__ FW,
    short* __restrict__ wbf) {
  const int idx = blockIdx.x * 256 + threadIdx.x;
  const int half = 262144;
  f32x4 v = (idx < half) ? *(const f32x4*)(EW + (size_t)idx * 4)
                         : *(const f32x4*)(FW + (size_t)(idx - half) * 4);
  u32x2 h = {cvtpk(v[0], v[1]), cvtpk(v[2], v[3])};
  *(u32x2*)(wbf + (size_t)idx * 4) = h;
}

// ---------------------------------------------------------------------------
// Stage 1 (v9): partial projections, d-split 2 blocks/CU. grid 512
// (XCD-chunked: each XCD one (p,s) -> W slice L2-resident), 512 thr = 8 waves.
// Block = (b,p,s,dh): out k 0..255 x d [dh*64,+64), n-chunk s*1024 (16 iters
// BK=64). LDS 80KB/block: W[256][64]bf16 x2 (global_load_lds, pre-swizzled
// src) + X^T[64][64] x2 (depth-2 reg prefetch + cvt_pk). No X duplication:
// each block loads only its 64-d half of X rows. Counted vmcnt (W=+4, X=+2),
// never 0 mid-loop. Two independent barrier domains per CU overlap phases.
// pws[b][p][s][k 256][d 128] f32 partials.
// ---------------------------------------------------------------------------
__global__ __launch_bounds__(512, 4) void proj_partial_kernel(
    const float* __restrict__ Kin, const float* __restrict__ Vin,
    const short* __restrict__ wbf, float* __restrict__ pws) {
  const int bid = blockIdx.x;                  // 0..511
  const int wk = (bid & 7) * 64 + (bid >> 3);  // XCD x owns wk [64x, 64x+64)
  const int dh = wk & 1;                       // d-half; pair co-XCD
  const int b = (wk >> 1) & 31;
  const int s = (wk >> 6) & 3;
  const int p = wk >> 8;

  const float* __restrict__ X =
      (p == 0 ? Kin : Vin) + (size_t)b * (N_SEQ * D_HEAD) + dh * 64;
  const short* __restrict__ wp = wbf + (size_t)p * (KP_DIM * N_SEQ);
  float* __restrict__ outp = pws + ((((size_t)b * 2 + p) * 4) + s) * (KP_DIM * D_HEAD)
                             + dh * 64;

  __shared__ __align__(16) short lw[2][KP_DIM * 64];  // 32KB x2: W [256 k][64 n]
  __shared__ __align__(16) short xt[2][64 * 64];      // 8KB x2: X^T [64 d][64 n]

  const int t = threadIdx.x;
  const int lane = t & 63;
  const int w = t >> 6;            // 0..7
  const int wkk = w * 32;          // wave k offset (8 slots of 32)
  const int l15 = lane & 15;
  const int l4 = lane >> 4;
  const int dq = t & 15;           // d-quad (0..15) within block's 64-d half
  const int rp = t >> 4;           // n row-pair (0..31)

  const int n0 = s * 1024;

  f32x4 acc[2][4];
#pragma unroll
  for (int i = 0; i < 2; ++i)
#pragma unroll
    for (int j = 0; j < 4; ++j) acc[i][j] = (f32x4){0.f, 0.f, 0.f, 0.f};

  f32x4 xA[2], xB[2];  // depth-2 X prefetch: 2 adjacent n-rows per thread

#define PROJ_WISSUE(BUF, NC)                                                        \
  do {                                                                              \
    _Pragma("unroll") for (int i_ = 0; i_ < 4; ++i_) {                              \
      int g_ = t + i_ * 512;                                                        \
      int row_ = g_ >> 3, c_ = g_ & 7;                                              \
      __builtin_amdgcn_global_load_lds(                                             \
          (const __attribute__((address_space(1))) void*)(wp + (size_t)row_ * N_SEQ \
              + (NC) + ((c_ ^ swz8(row_)) << 3)),                                   \
          (__attribute__((address_space(3))) void*)(&lw[BUF][g_ * 8]), 16, 0, 0);   \
    }                                                                               \
  } while (0)

#define PROJ_XISSUE(XR, NC)                                                         \
  do {                                                                              \
    _Pragma("unroll") for (int i_ = 0; i_ < 2; ++i_)                                \
      XR[i_] = *(const f32x4*)(X + (size_t)((NC) + rp * 2 + i_) * D_HEAD + dq * 4); \
  } while (0)

#define PROJ_XCVT(XR, BUF)                                                          \
  do {                                                                              \
    _Pragma("unroll") for (int j_ = 0; j_ < 4; ++j_) {                              \
      int drow_ = dq * 4 + j_;                                                      \
      unsigned int hv_ = cvtpk(XR[0][j_], XR[1][j_]);                               \
      *(unsigned int*)(&xt[BUF][drow_ * 64 + ((rp * 2) ^ (swz8(drow_) << 3))]) = hv_; \
    }                                                                               \
  } while (0)

#define PROJ_COMPUTE(CUR)                                                           \
  do {                                                                              \
    _Pragma("unroll") for (int ks2 = 0; ks2 < 2; ++ks2) {                           \
      const int col0 = ks2 * 32 + l4 * 8;                                           \
      bf16x8 a_[2], bb_[4];                                                         \
      _Pragma("unroll") for (int mt_ = 0; mt_ < 2; ++mt_) {                         \
        int row_ = wkk + mt_ * 16 + l15;                                            \
        a_[mt_] = *(const bf16x8*)(&lw[CUR][row_ * 64 + (col0 ^ (swz8(row_) << 3))]); \
      }                                                                             \
      _Pragma("unroll") for (int nt_ = 0; nt_ < 4; ++nt_) {                         \
        int row_ = nt_ * 16 + l15;                                                  \
        bb_[nt_] = *(const bf16x8*)(&xt[CUR][row_ * 64 + (col0 ^ (swz8(row_) << 3))]); \
      }                                                                             \
      _Pragma("unroll") for (int mt_ = 0; mt_ < 2; ++mt_)                           \
        _Pragma("unroll") for (int nt_ = 0; nt_ < 4; ++nt_)                         \
          acc[mt_][nt_] = __builtin_amdgcn_mfma_f32_16x16x32_bf16(a_[mt_], bb_[nt_], \
                                                                  acc[mt_][nt_], 0, 0, 0); \
    }                                                                               \
  } while (0)

  // ---- prologue ----
  PROJ_XISSUE(xA, n0);                                   // X(0): +2
  PROJ_WISSUE(0, n0);                                    // W(0): +4
  asm volatile("s_waitcnt vmcnt(4)" ::: "memory");       // X(0) done
  PROJ_XCVT(xA, 0);
  PROJ_XISSUE(xB, n0 + 64);                              // X(1): +2
  asm volatile("s_waitcnt vmcnt(2)" ::: "memory");       // W(0) done, X(1) flies
  __syncthreads();

  // ---- main loop: iters 0..13 as 7 even/odd pairs ----
  for (int itp = 0; itp < 7; ++itp) {
    const int it0 = itp * 2;
    // even iter (cur=0)
    PROJ_WISSUE(1, n0 + (it0 + 1) * 64);                 // W(it+1): +4
    PROJ_XISSUE(xA, n0 + (it0 + 2) * 64);                // X(it+2): +2
    PROJ_COMPUTE(0);
    asm volatile("s_waitcnt vmcnt(6)" ::: "memory");     // X(it+1) done
    PROJ_XCVT(xB, 1);
    asm volatile("s_waitcnt vmcnt(2)" ::: "memory");     // W(it+1) done
    __syncthreads();
    // odd iter (cur=1)
    PROJ_WISSUE(0, n0 + (it0 + 2) * 64);
    PROJ_XISSUE(xB, n0 + (it0 + 3) * 64);
    PROJ_COMPUTE(1);
    asm volatile("s_waitcnt vmcnt(6)" ::: "memory");
    PROJ_XCVT(xA, 0);
    asm volatile("s_waitcnt vmcnt(2)" ::: "memory");
    __syncthreads();
  }
  // ---- it=14 (cur=0) ----
  PROJ_WISSUE(1, n0 + 15 * 64);                          // W(15): +4
  PROJ_COMPUTE(0);
  asm volatile("s_waitcnt vmcnt(4)" ::: "memory");       // X(15) done
  PROJ_XCVT(xB, 1);
  asm volatile("s_waitcnt vmcnt(0)" ::: "memory");       // W(15) done
  __syncthreads();
  // ---- it=15 (cur=1) ----
  PROJ_COMPUTE(1);

#undef PROJ_WISSUE
#undef PROJ_XISSUE
#undef PROJ_XCVT
#undef PROJ_COMPUTE

  // ---- write f32 partials (k 0..255 x this block's 64-d half) ----
#pragma unroll
  for (int mt = 0; mt < 2; ++mt)
#pragma unroll
    for (int nt = 0; nt < 4; ++nt)
#pragma unroll
      for (int r = 0; r < 4; ++r) {
        int kk = wkk + mt * 16 + l4 * 4 + r;
        int dd = nt * 16 + l15;
        outp[kk * D_HEAD + dd] = acc[mt][nt][r];
      }
}

// ---------------------------------------------------------------------------
// Stage 1b: reduce 4 partials + bias. grid 128 (unchanged).
// ---------------------------------------------------------------------------
__global__ __launch_bounds__(256) void reduce_bias_kernel(
    const float* __restrict__ pws, const float* __restrict__ Eb,
    const float* __restrict__ Fb, short* __restrict__ kp, short* __restrict__ vpt) {
  const int sub = blockIdx.x & 3;
  const int b = blockIdx.x >> 2;
  const int t = threadIdx.x;
  __shared__ short tile[128 * 128];
  if (sub < 2) {
    const float* __restrict__ base = pws + ((size_t)b * 2) * 4 * 32768;
    const int off = sub * 16384;
    for (int i = t; i < 16384; i += 256) {
      int ii = off + i;
      int k = ii >> 7;
      float v = base[ii] + base[ii + 32768] + base[ii + 65536] + base[ii + 98304] + Eb[k];
      kp[(size_t)b * 32768 + ii] = f2bf(v);
    }
  } else {
    const int kh = sub - 2;
    const float* __restrict__ base = pws + (((size_t)b * 2 + 1) * 4) * 32768 + kh * 16384;
    for (int i = t; i < 16384; i += 256) {
      int kl = i >> 7, d = i & 127;
      float v = base[i] + base[i + 32768] + base[i + 65536] + base[i + 98304] + Fb[kh * 128 + kl];
      tile[kl * 128 + (d ^ ((kl & 15) << 3))] = f2bf(v);
    }
    __syncthreads();
    for (int i = t; i < 16384; i += 256) {
      int d = i >> 7, kl = i & 127;
      vpt[(size_t)b * 32768 + d * 256 + kh * 128 + kl] = tile[kl * 128 + (d ^ ((kl & 15) << 3))];
    }
  }
}

// ---------------------------------------------------------------------------
// Stage 2: attention v4 (unchanged, verified). grid 256, 1024 thr,
// __launch_bounds__(1024,4), 160KB LDS, zero mid-loop barriers.
// ---------------------------------------------------------------------------
__global__ __launch_bounds__(1024, 4) void attn_kernel(
    const float* __restrict__ Q, const short* __restrict__ kp,
    const short* __restrict__ vpt, float* __restrict__ out) {
  const int bid = blockIdx.x;
  const int wk = (bid & 7) * 32 + (bid >> 3);  // XCD-chunked: 4 b's per XCD
  const int b = wk >> 3;
  const int slice = wk & 7;
  const int t = threadIdx.x;
  const int lane = t & 63;
  const int w = t >> 6;  // 0..15
  const int l15 = lane & 15, l4 = lane >> 4;

  __shared__ __align__(16) short lbuf[81920];
  short* lkp = lbuf;
  short* lvpt = lbuf + 32768;
  short* lpw = lbuf + 65536 + w * 1024;  // 2KB/wave

  const short* __restrict__ kpb = kp + (size_t)b * 32768;
  const short* __restrict__ vptb = vpt + (size_t)b * 32768;

#pragma unroll
  for (int i = 0; i < 4; ++i) {
    int g = t + i * 1024;
    int row = g >> 4, c = g & 15;
    __builtin_amdgcn_global_load_lds(
        (const __attribute__((address_space(1))) void*)(kpb + (size_t)row * 128 +
                                                        ((c ^ (row & 7)) << 3)),
        (__attribute__((address_space(3))) void*)(&lkp[g * 8]), 16, 0, 0);
  }
#pragma unroll
  for (int i = 0; i < 4; ++i) {
    int g = t + i * 1024;
    int row = g >> 5, c = g & 31;
    __builtin_amdgcn_global_load_lds(
        (const __attribute__((address_space(1))) void*)(vptb + (size_t)row * 256 +
                                                        ((c ^ (row & 7)) << 3)),
        (__attribute__((address_space(3))) void*)(&lvpt[g * 8]), 16, 0, 0);
  }

  const float scale = 0.08838834764831845f;  // 1/sqrt(128)
  f32x4 qraw[8];
  {
    const float* qr = Q + ((size_t)b * N_SEQ + slice * 512 + w * 16 + l15) * D_HEAD;
#pragma unroll
    for (int ks = 0; ks < 4; ++ks) {
      qraw[2 * ks] = *(const f32x4*)(qr + ks * 32 + l4 * 8);
      qraw[2 * ks + 1] = *(const f32x4*)(qr + ks * 32 + l4 * 8 + 4);
    }
  }
  asm volatile("s_waitcnt vmcnt(0)" ::: "memory");
  __syncthreads();

#pragma unroll
  for (int rd = 0; rd < 2; ++rd) {
    const int rowBase = slice * 512 + rd * 256 + w * 16;

    bf16x8 qf[4];
#pragma unroll
    for (int ks = 0; ks < 4; ++ks) {
      union { unsigned int u[4]; bf16x8 v; } cv;
      cv.u[0] = cvtpk(qraw[2 * ks][0] * scale, qraw[2 * ks][1] * scale);
      cv.u[1] = cvtpk(qraw[2 * ks][2] * scale, qraw[2 * ks][3] * scale);
      cv.u[2] = cvtpk(qraw[2 * ks + 1][0] * scale, qraw[2 * ks + 1][1] * scale);
      cv.u[3] = cvtpk(qraw[2 * ks + 1][2] * scale, qraw[2 * ks + 1][3] * scale);
      qf[ks] = cv.v;
    }

    f32x4 accs[16];
#pragma unroll
    for (int i = 0; i < 16; ++i) accs[i] = (f32x4){0.f, 0.f, 0.f, 0.f};
#pragma unroll
    for (int ks = 0; ks < 4; ++ks) {
#pragma unroll
      for (int nt = 0; nt < 16; ++nt) {
        bf16x8 af = *(const bf16x8*)(&lkp[(nt * 16 + l15) * 128 +
                                          (((ks * 4 + l4) ^ (l15 & 7)) << 3)]);
        accs[nt] = __builtin_amdgcn_mfma_f32_16x16x32_bf16(af, qf[ks], accs[nt], 0, 0, 0);
      }
    }

    float m = -1e30f;
#pragma unroll
    for (int nt = 0; nt < 16; ++nt)
#pragma unroll
      for (int r = 0; r < 4; ++r) m = fmaxf(m, accs[nt][r]);
    m = fmaxf(m, __shfl_xor(m, 16));
    m = fmaxf(m, __shfl_xor(m, 32));
    float s = 0.f;
#pragma unroll
    for (int nt = 0; nt < 16; ++nt)
#pragma unroll
      for (int r = 0; r < 4; ++r) {
        float e = __expf(accs[nt][r] - m);
        accs[nt][r] = e;
        s += e;
      }
    s += __shfl_xor(s, 16);
    s += __shfl_xor(s, 32);
    float inv = 1.0f / s;

    f32x4 acco[8];
#pragma unroll
    for (int i = 0; i < 8; ++i) acco[i] = (f32x4){0.f, 0.f, 0.f, 0.f};
#pragma unroll
    for (int qq = 0; qq < 4; ++qq) {
#pragma unroll
      for (int ntl = 0; ntl < 4; ++ntl) {
        int nt = qq * 4 + ntl;
        int cw = 2 * ntl + (l4 >> 1);
        unsigned int p0 = cvtpk(accs[nt][0] * inv, accs[nt][1] * inv);
        unsigned int p1 = cvtpk(accs[nt][2] * inv, accs[nt][3] * inv);
        *(u32x2*)((char*)lpw + l15 * 128 + ((cw ^ (l15 & 7)) << 4) + (l4 & 1) * 8) =
            (u32x2){p0, p1};
      }
      if (rd == 0 && qq == 3) {
        const float* qr = Q + ((size_t)b * N_SEQ + slice * 512 + 256 + w * 16 + l15) * D_HEAD;
#pragma unroll
        for (int ks = 0; ks < 4; ++ks) {
          qraw[2 * ks] = *(const f32x4*)(qr + ks * 32 + l4 * 8);
          qraw[2 * ks + 1] = *(const f32x4*)(qr + ks * 32 + l4 * 8 + 4);
        }
      }
#pragma unroll
      for (int ksl = 0; ksl < 2; ++ksl) {
        bf16x8 pa = *(const bf16x8*)((char*)lpw + l15 * 128 +
                                     (((4 * ksl + l4) ^ (l15 & 7)) << 4));
        int ksa = qq * 2 + ksl;
#pragma unroll
        for (int ntv = 0; ntv < 8; ++ntv) {
          bf16x8 av = *(const bf16x8*)(&lvpt[(ntv * 16 + l15) * 256 +
                                             (((ksa * 4 + l4) ^ (l15 & 7)) << 3)]);
          acco[ntv] = __builtin_amdgcn_mfma_f32_16x16x32_bf16(av, pa, acco[ntv], 0, 0, 0);
        }
      }
    }

    float* ob = out + ((size_t)b * N_SEQ + rowBase) * D_HEAD;
#pragma unroll
    for (int ntv = 0; ntv < 8; ++ntv)
      *(f32x4*)(ob + (size_t)l15 * D_HEAD + ntv * 16 + l4 * 4) = acco[ntv];
  }
}

// ---------------------------------------------------------------------------
extern "C" void kernel_launch(void* const* d_in, const int* in_sizes, int n_in,
                              void* d_out, int out_size, void* d_ws, size_t ws_size,
                              hipStream_t stream) {
  const float* Q  = (const float*)d_in[0];
  const float* K  = (const float*)d_in[1];
  const float* V  = (const float*)d_in[2];
  const float* EW = (const float*)d_in[3];
  const float* Eb = (const float*)d_in[4];
  const float* FW = (const float*)d_in[5];
  const float* Fb = (const float*)d_in[6];
  float* out = (float*)d_out;

  // d_out scratch (dead before attn writes): [0,4MB) wbf; [8MB,41.5MB) pws
  short* wbf = (short*)d_out;
  float* pws = (float*)d_out + 2097152;
  short* kpb = (short*)d_ws;
  short* vpt = (short*)((char*)d_ws + (size_t)32 * KP_DIM * D_HEAD * 2);

  conv_w_kernel<<<dim3(2048), dim3(256), 0, stream>>>(EW, FW, wbf);
  proj_partial_kernel<<<dim3(512), dim3(512), 0, stream>>>(K, V, wbf, pws);
  reduce_bias_kernel<<<dim3(128), dim3(256), 0, stream>>>(pws, Eb, Fb, kpb, vpt);
  attn_kernel<<<dim3(256), dim3(1024), 0, stream>>>(Q, kpb, vpt, out);
}